// Round 7
// baseline (228.492 us; speedup 1.0000x reference)
//
#include <hip/hip_runtime.h>

#define N_EDGES 1600000
#define N_NODES 50000
#define D_FEAT  32

// ---- workspace layout (bytes) ----
// offs: int[N_NODES+1]; rank: int[N_EDGES]; perm: int[N_EDGES]
#define OFFS_BYTES   ((N_NODES + 1) * 4)
#define RANK_OFF     ((size_t)(((OFFS_BYTES + 255) / 256) * 256))
#define PERM_OFF     (RANK_OFF + (size_t)N_EDGES * 4)
#define WS_NEEDED    (PERM_OFF + (size_t)N_EDGES * 4)

__global__ void zero_counts_kernel(int* __restrict__ cnt) {
    int i = blockIdx.x * blockDim.x + threadIdx.x;
    if (i <= N_NODES) cnt[i] = 0;
}

// Returning atomic + coalesced rank store. 2048-block grid-stride: each
// thread pipelines ~3 independent atomic chains while staying resident —
// measured ~2x faster than one-thread-per-edge (round 2 vs round 6).
__global__ void hist_rank_kernel(const int* __restrict__ index,
                                 int* __restrict__ cnt,
                                 int* __restrict__ rank) {
    int e = blockIdx.x * blockDim.x + threadIdx.x;
    int stride = gridDim.x * blockDim.x;
    for (; e < N_EDGES; e += stride)
        rank[e] = atomicAdd(&cnt[index[e]], 1);
}

// Single-block in-place exclusive scan: counts -> offsets.
__global__ __launch_bounds__(1024) void scan_offsets_kernel(int* __restrict__ cnt) {
    const int T = 1024;
    const int C = (N_NODES + T - 1) / T;  // 49 per thread
    __shared__ int part[T];
    int t = threadIdx.x;
    int base = t * C;
    int s = 0;
    for (int j = 0; j < C; ++j) {
        int i = base + j;
        if (i < N_NODES) s += cnt[i];
    }
    part[t] = s;
    __syncthreads();
    int v = s;
    for (int d = 1; d < T; d <<= 1) {
        int w = (t >= d) ? part[t - d] : 0;
        __syncthreads();
        v += w;
        part[t] = v;
        __syncthreads();
    }
    int run = v - s;
    for (int j = 0; j < C; ++j) {
        int i = base + j;
        if (i < N_NODES) {
            int c = cnt[i];
            cnt[i] = run;
            run += c;
        }
    }
    if (t == T - 1) cnt[N_NODES] = v;
}

// Pure streaming pass, 2048-block grid-stride (round-2 proven shape):
// coalesced index+rank loads, cached offs gather, independent scattered store.
__global__ void build_perm_kernel(const int* __restrict__ index,
                                  const int* __restrict__ offs,
                                  const int* __restrict__ rank,
                                  int* __restrict__ perm) {
    int e = blockIdx.x * blockDim.x + threadIdx.x;
    int stride = gridDim.x * blockDim.x;
    for (; e < N_EDGES; e += stride)
        perm[offs[index[e]] + rank[e]] = e;
}

// One wave per node; lane = slot*8 + f4. 4-deep unroll -> 32 independent
// 128B row loads in flight per wave. (Reconstructed ~20-45 us.)
__global__ void gather_sum_kernel(const float4* __restrict__ src4,
                                  const int* __restrict__ perm,
                                  const int* __restrict__ offs,
                                  const float4* __restrict__ out_in4,
                                  float4* __restrict__ out4) {
    int wave = threadIdx.x >> 6;
    int node = blockIdx.x * 4 + wave;
    if (node >= N_NODES) return;
    int lane = threadIdx.x & 63;
    int slot = lane >> 3;
    int f4   = lane & 7;
    int start = offs[node];
    int end   = offs[node + 1];

    float4 a0 = {0,0,0,0}, a1 = {0,0,0,0}, a2 = {0,0,0,0}, a3 = {0,0,0,0};
    int i = start + slot;
    for (; i + 24 < end; i += 32) {
        int e0 = perm[i];
        int e1 = perm[i + 8];
        int e2 = perm[i + 16];
        int e3 = perm[i + 24];
        float4 v0 = src4[(size_t)e0 * 8 + f4];
        float4 v1 = src4[(size_t)e1 * 8 + f4];
        float4 v2 = src4[(size_t)e2 * 8 + f4];
        float4 v3 = src4[(size_t)e3 * 8 + f4];
        a0.x += v0.x; a0.y += v0.y; a0.z += v0.z; a0.w += v0.w;
        a1.x += v1.x; a1.y += v1.y; a1.z += v1.z; a1.w += v1.w;
        a2.x += v2.x; a2.y += v2.y; a2.z += v2.z; a2.w += v2.w;
        a3.x += v3.x; a3.y += v3.y; a3.z += v3.z; a3.w += v3.w;
    }
    for (; i < end; i += 8) {
        int e0 = perm[i];
        float4 v0 = src4[(size_t)e0 * 8 + f4];
        a0.x += v0.x; a0.y += v0.y; a0.z += v0.z; a0.w += v0.w;
    }
    a0.x += a1.x + a2.x + a3.x;
    a0.y += a1.y + a2.y + a3.y;
    a0.z += a1.z + a2.z + a3.z;
    a0.w += a1.w + a2.w + a3.w;

    for (int m = 8; m <= 32; m <<= 1) {
        a0.x += __shfl_xor(a0.x, m, 64);
        a0.y += __shfl_xor(a0.y, m, 64);
        a0.z += __shfl_xor(a0.z, m, 64);
        a0.w += __shfl_xor(a0.w, m, 64);
    }
    if (slot == 0) {
        size_t o = (size_t)node * 8 + f4;
        float4 b = out_in4[o];
        b.x += a0.x; b.y += a0.y; b.z += a0.z; b.w += a0.w;
        out4[o] = b;
    }
}

// ---- fallback (round-1 proven path) if ws is too small ----
__global__ void init_out_kernel(const float4* __restrict__ out_in,
                                float4* __restrict__ out, int n4) {
    int i = blockIdx.x * blockDim.x + threadIdx.x;
    int stride = gridDim.x * blockDim.x;
    for (; i < n4; i += stride) out[i] = out_in[i];
}
__global__ void scatter_add_kernel(const float4* __restrict__ src,
                                   const int* __restrict__ index,
                                   float* __restrict__ out) {
    const int total = N_EDGES * 8;
    int t = blockIdx.x * blockDim.x + threadIdx.x;
    int stride = gridDim.x * blockDim.x;
    for (; t < total; t += stride) {
        int e = t >> 3;
        int f = t & 7;
        float4 v = src[t];
        int node = index[e];
        float* o = out + (size_t)node * D_FEAT + f * 4;
        atomicAdd(o + 0, v.x);
        atomicAdd(o + 1, v.y);
        atomicAdd(o + 2, v.z);
        atomicAdd(o + 3, v.w);
    }
}

extern "C" void kernel_launch(void* const* d_in, const int* in_sizes, int n_in,
                              void* d_out, int out_size, void* d_ws, size_t ws_size,
                              hipStream_t stream) {
    const float* src    = (const float*)d_in[0];
    const int*   index  = (const int*)d_in[1];
    const float* out_in = (const float*)d_in[2];
    float* out          = (float*)d_out;

    if (ws_size < WS_NEEDED) {
        int n4 = out_size / 4;
        init_out_kernel<<<2048, 256, 0, stream>>>((const float4*)out_in, (float4*)out, n4);
        scatter_add_kernel<<<2048, 256, 0, stream>>>((const float4*)src, index, out);
        return;
    }

    char* ws = (char*)d_ws;
    int* offs = (int*)ws;
    int* rank = (int*)(ws + RANK_OFF);
    int* perm = (int*)(ws + PERM_OFF);

    zero_counts_kernel<<<(N_NODES + 256) / 256, 256, 0, stream>>>(offs);
    hist_rank_kernel<<<2048, 256, 0, stream>>>(index, offs, rank);
    scan_offsets_kernel<<<1, 1024, 0, stream>>>(offs);
    build_perm_kernel<<<2048, 256, 0, stream>>>(index, offs, rank, perm);
    gather_sum_kernel<<<(N_NODES + 3) / 4, 256, 0, stream>>>(
        (const float4*)src, perm, offs, (const float4*)out_in, (float4*)out);
}

// Round 8
// 170.923 us; speedup vs baseline: 1.3368x; 1.3368x over previous
//
#include <hip/hip_runtime.h>

#define N_EDGES 1600000
#define N_NODES 50000
#define D_FEAT  32

// Copy the "out" input (accumulator base) into d_out, vectorized float4.
__global__ void init_out_kernel(const float4* __restrict__ out_in,
                                float4* __restrict__ out, int n4) {
    int i = blockIdx.x * blockDim.x + threadIdx.x;
    int stride = gridDim.x * blockDim.x;
    for (; i < n4; i += stride) out[i] = out_in[i];
}

// Direct scatter-add, line-friendly layout: thread i -> (edge i>>5, feat i&31).
// Each 32-lane half-wave covers one FULL 128B node row contiguously, so one
// atomic instruction touches ~4 cache lines (2 edges x 2 lines) instead of
// round-1's ~16. Atomics are fire-and-forget (non-returning); src loads are
// perfectly coalesced scalar floats; index[e] broadcasts across 32 lanes.
__global__ void scatter_direct_kernel(const float* __restrict__ src,
                                      const int* __restrict__ index,
                                      float* __restrict__ out) {
    const long total = (long)N_EDGES * D_FEAT;       // 51.2M
    long i = (long)blockIdx.x * blockDim.x + threadIdx.x;
    const long stride = (long)gridDim.x * blockDim.x;
    for (; i < total; i += stride) {
        int e = (int)(i >> 5);
        int f = (int)(i & 31);
        float v = src[i];                            // contiguous: src[e*32+f]
        int node = index[e];
        atomicAdd(&out[(size_t)node * D_FEAT + f], v);
    }
}

extern "C" void kernel_launch(void* const* d_in, const int* in_sizes, int n_in,
                              void* d_out, int out_size, void* d_ws, size_t ws_size,
                              hipStream_t stream) {
    const float* src    = (const float*)d_in[0];
    const int*   index  = (const int*)d_in[1];
    const float* out_in = (const float*)d_in[2];
    float* out          = (float*)d_out;

    // 1) out = out_input (also clears poison each call; deterministic per call)
    int n4 = out_size / 4;                           // 400K float4
    init_out_kernel<<<1563, 256, 0, stream>>>((const float4*)out_in, (float4*)out, n4);

    // 2) one-pass direct atomic scatter, full-residency grid-stride
    //    (2048 blocks x 256 thr = 524K threads, ~98 independent iters each)
    scatter_direct_kernel<<<2048, 256, 0, stream>>>(src, index, out);
}